// Round 2
// baseline (1594.165 us; speedup 1.0000x reference)
//
#include <hip/hip_runtime.h>

#define FDIM 128

// One thread per edge: histogram in-degree.
__global__ void degree_kernel(const int* __restrict__ dst, float* __restrict__ cnt, int E) {
    int e = blockIdx.x * blockDim.x + threadIdx.x;
    if (e < E) atomicAdd(&cnt[dst[e]], 1.0f);
}

// 64 threads (one wave) per edge; each lane moves a float2 (512B/edge contiguous).
__global__ void scatter_kernel(const float* __restrict__ x, const int* __restrict__ src,
                               const int* __restrict__ dst, float* __restrict__ msg, int E) {
    int gt = blockIdx.x * blockDim.x + threadIdx.x;
    int e = gt >> 6;
    int lane = gt & 63;
    if (e >= E) return;
    int s = src[e];   // wave-uniform -> scalar load
    int d = dst[e];
    float2 v = reinterpret_cast<const float2*>(x + (size_t)s * FDIM)[lane];
    float* md = msg + (size_t)d * FDIM + 2 * lane;
    atomicAdd(md, v.x);
    atomicAdd(md + 1, v.y);
}

// out[i][j] = sum_k (agg[i][k]/max(cnt[i],1))*Wl[k][j] + xin[i][k]*Wr[k][j] + b[j]
// 16 rows per block, 256 threads: thread (rh=tid>>7, j=tid&127) computes 8 rows at column j.
// Safe when out aliases agg: each block stages ONLY ITS OWN 16 rows into LDS (+barrier)
// before writing the same 16 rows.
template <bool RELU>
__global__ void gemm_kernel(const float* agg, const float* __restrict__ cnt,
                            const float* __restrict__ xin, const float* __restrict__ Wl,
                            const float* __restrict__ Wr, const float* __restrict__ bias,
                            float* out, int n) {
    const int ROWS = 16;
    __shared__ float m_s[ROWS][FDIM];
    __shared__ float x_s[ROWS][FDIM];
    int tid = threadIdx.x;
    int row0 = blockIdx.x * ROWS;

    // Stage 16 rows of mean (=agg/max(cnt,1)) and xin.
    // 16 rows * 32 float4/row = 512 float4 slots over 256 threads -> 2 iterations.
#pragma unroll
    for (int i = 0; i < 2; ++i) {
        int idx4 = tid + i * 256;     // [0, 512)
        int r = idx4 >> 5;            // [0, 16)  -- 32 float4 per row
        int c4 = idx4 & 31;
        int row = row0 + r;
        if (row < n) {
            float inv = 1.0f / fmaxf(cnt[row], 1.0f);
            float4 mv = reinterpret_cast<const float4*>(agg + (size_t)row * FDIM)[c4];
            float4 xv = reinterpret_cast<const float4*>(xin + (size_t)row * FDIM)[c4];
            float* mp = &m_s[r][c4 * 4];
            mp[0] = mv.x * inv; mp[1] = mv.y * inv; mp[2] = mv.z * inv; mp[3] = mv.w * inv;
            float* xp = &x_s[r][c4 * 4];
            xp[0] = xv.x; xp[1] = xv.y; xp[2] = xv.z; xp[3] = xv.w;
        }
    }
    __syncthreads();

    int j = tid & 127;
    int rh = tid >> 7;  // 0 or 1
    float acc[8];
    float bj = bias[j];
#pragma unroll
    for (int r = 0; r < 8; ++r) acc[r] = bj;

#pragma unroll 4
    for (int k = 0; k < FDIM; ++k) {
        float wl = Wl[k * FDIM + j];   // wave-coalesced 256B; L2-resident
        float wr = Wr[k * FDIM + j];
#pragma unroll
        for (int r = 0; r < 8; ++r) {  // LDS broadcasts (uniform addr) — conflict-free
            acc[r] += m_s[rh * 8 + r][k] * wl + x_s[rh * 8 + r][k] * wr;
        }
    }

#pragma unroll
    for (int r = 0; r < 8; ++r) {
        int row = row0 + rh * 8 + r;
        if (row < n) {
            float v = acc[r];
            if (RELU) v = fmaxf(v, 0.0f);
            out[(size_t)row * FDIM + j] = v;
        }
    }
}

extern "C" void kernel_launch(void* const* d_in, const int* in_sizes, int n_in,
                              void* d_out, int out_size, void* d_ws, size_t ws_size,
                              hipStream_t stream) {
    const float* x   = (const float*)d_in[0];
    const int*   ei  = (const int*)d_in[1];   // JAX x64 disabled -> int32 on device
    const float* Wl0 = (const float*)d_in[2];
    const float* Wr0 = (const float*)d_in[3];
    const float* b0  = (const float*)d_in[4];
    const float* Wl1 = (const float*)d_in[5];
    const float* Wr1 = (const float*)d_in[6];
    const float* b1  = (const float*)d_in[7];

    int N = in_sizes[0] / FDIM;   // 50000
    int E = in_sizes[1] / 2;      // 800000
    const int* src = ei;
    const int* dst = ei + E;

    float* cnt = (float*)d_ws;                         // N floats
    float* h   = (float*)((char*)d_ws + (1 << 18));    // N*FDIM floats at +256KB
    float* msg = (float*)d_out;                        // reuse output buffer as msg_sum

    size_t featBytes = (size_t)N * FDIM * sizeof(float);
    int gemmBlocks = (N + 15) / 16;

    // in-degree (shared by both layers)
    hipMemsetAsync(cnt, 0, (size_t)N * sizeof(float), stream);
    degree_kernel<<<(E + 255) / 256, 256, 0, stream>>>(dst, cnt, E);

    // ---- layer 0 ----
    hipMemsetAsync(msg, 0, featBytes, stream);
    scatter_kernel<<<(E * 64 + 255) / 256, 256, 0, stream>>>(x, src, dst, msg, E);
    gemm_kernel<true><<<gemmBlocks, 256, 0, stream>>>(msg, cnt, x, Wl0, Wr0, b0, h, N);

    // ---- layer 1 ----
    hipMemsetAsync(msg, 0, featBytes, stream);
    scatter_kernel<<<(E * 64 + 255) / 256, 256, 0, stream>>>(h, src, dst, msg, E);
    gemm_kernel<false><<<gemmBlocks, 256, 0, stream>>>(msg, cnt, h, Wl1, Wr1, b1, msg, N);
}

// Round 3
// 414.572 us; speedup vs baseline: 3.8453x; 3.8453x over previous
//
#include <hip/hip_runtime.h>

#define FDIM 128

// ======================= CSR build =======================
__global__ void hist_kernel(const int* __restrict__ dst, int* __restrict__ deg, int E) {
    int e = blockIdx.x * blockDim.x + threadIdx.x;
    if (e < E) atomicAdd(&deg[dst[e]], 1);
}

// per-256-block exclusive scan; block totals to bsum
__global__ void scan1_kernel(const int* __restrict__ deg, int* __restrict__ rp,
                             int* __restrict__ bsum, int N) {
    __shared__ int s[256];
    int i = blockIdx.x * 256 + threadIdx.x;
    int v = (i < N) ? deg[i] : 0;
    s[threadIdx.x] = v;
    __syncthreads();
    for (int off = 1; off < 256; off <<= 1) {
        int t = (threadIdx.x >= off) ? s[threadIdx.x - off] : 0;
        __syncthreads();
        s[threadIdx.x] += t;
        __syncthreads();
    }
    if (i < N) rp[i] = s[threadIdx.x] - v;          // exclusive
    if (threadIdx.x == 255) bsum[blockIdx.x] = s[255];
}

// single-block exclusive scan of block sums (nb <= 256)
__global__ void scan2_kernel(int* __restrict__ bsum, int nb) {
    __shared__ int s[256];
    int v = (threadIdx.x < (unsigned)nb) ? bsum[threadIdx.x] : 0;
    s[threadIdx.x] = v;
    __syncthreads();
    for (int off = 1; off < 256; off <<= 1) {
        int t = (threadIdx.x >= off) ? s[threadIdx.x - off] : 0;
        __syncthreads();
        s[threadIdx.x] += t;
        __syncthreads();
    }
    if (threadIdx.x < (unsigned)nb) bsum[threadIdx.x] = s[threadIdx.x] - v;
}

__global__ void scan3_kernel(int* __restrict__ rp, const int* __restrict__ bsum,
                             int* __restrict__ cursor, int N, int E) {
    int i = blockIdx.x * 256 + threadIdx.x;
    if (i < N) {
        int v = rp[i] + bsum[blockIdx.x];
        rp[i] = v;
        cursor[i] = v;
    } else if (i == N) {
        rp[N] = E;
    }
}

__global__ void fill_kernel(const int* __restrict__ src, const int* __restrict__ dst,
                            int* __restrict__ cursor, int* __restrict__ eid, int E) {
    int e = blockIdx.x * blockDim.x + threadIdx.x;
    if (e < E) {
        int p = atomicAdd(&cursor[dst[e]], 1);
        eid[p] = src[e];
    }
}

// ============ mean-aggregate via gather: one wave per node ============
// Lane l accumulates columns {2l, 2l+1}; each edge row read is one coalesced
// 512B wave transaction. 4-deep unroll for outstanding loads.
__global__ void gather_kernel(const float* __restrict__ x, const int* __restrict__ rp,
                              const int* __restrict__ eid, float* __restrict__ mean, int N) {
    int node = blockIdx.x * (blockDim.x >> 6) + (threadIdx.x >> 6);
    int lane = threadIdx.x & 63;
    if (node >= N) return;
    int beg = rp[node], end = rp[node + 1];
    float ax = 0.f, ay = 0.f;
    int k = beg;
    for (; k + 4 <= end; k += 4) {
        int s0 = eid[k], s1 = eid[k + 1], s2 = eid[k + 2], s3 = eid[k + 3];
        float2 v0 = reinterpret_cast<const float2*>(x + (size_t)s0 * FDIM)[lane];
        float2 v1 = reinterpret_cast<const float2*>(x + (size_t)s1 * FDIM)[lane];
        float2 v2 = reinterpret_cast<const float2*>(x + (size_t)s2 * FDIM)[lane];
        float2 v3 = reinterpret_cast<const float2*>(x + (size_t)s3 * FDIM)[lane];
        ax += v0.x + v1.x + v2.x + v3.x;
        ay += v0.y + v1.y + v2.y + v3.y;
    }
    for (; k < end; ++k) {
        int s = eid[k];
        float2 v = reinterpret_cast<const float2*>(x + (size_t)s * FDIM)[lane];
        ax += v.x;
        ay += v.y;
    }
    float inv = (end > beg) ? 1.0f / (float)(end - beg) : 0.0f;  // isolated -> 0
    reinterpret_cast<float2*>(mean + (size_t)node * FDIM)[lane] = make_float2(ax * inv, ay * inv);
}

// ===================== fallback: atomic scatter (R2 path) =====================
__global__ void degree_kernel(const int* __restrict__ dst, float* __restrict__ cnt, int E) {
    int e = blockIdx.x * blockDim.x + threadIdx.x;
    if (e < E) atomicAdd(&cnt[dst[e]], 1.0f);
}

__global__ void scatter_kernel(const float* __restrict__ x, const int* __restrict__ src,
                               const int* __restrict__ dst, float* __restrict__ msg, int E) {
    int gt = blockIdx.x * blockDim.x + threadIdx.x;
    int e = gt >> 6;
    int lane = gt & 63;
    if (e >= E) return;
    int s = src[e];
    int d = dst[e];
    float2 v = reinterpret_cast<const float2*>(x + (size_t)s * FDIM)[lane];
    float* md = msg + (size_t)d * FDIM + 2 * lane;
    atomicAdd(md, v.x);
    atomicAdd(md + 1, v.y);
}

// ===================== fused epilogue GEMM =====================
// out[i][j] = sum_k scale(agg[i][k])*Wl[k][j] + xin[i][k]*Wr[k][j] + b[j]
// cnt==nullptr -> agg is already the mean (scale=1, exact).
// In-place safe (out may alias agg): block stages only its own 16 rows.
template <bool RELU>
__global__ void gemm_kernel(const float* agg, const float* cnt,
                            const float* __restrict__ xin, const float* __restrict__ Wl,
                            const float* __restrict__ Wr, const float* __restrict__ bias,
                            float* out, int n) {
    const int ROWS = 16;
    __shared__ float m_s[ROWS][FDIM];
    __shared__ float x_s[ROWS][FDIM];
    int tid = threadIdx.x;
    int row0 = blockIdx.x * ROWS;

#pragma unroll
    for (int i = 0; i < 2; ++i) {
        int idx4 = tid + i * 256;     // [0, 512)
        int r = idx4 >> 5;            // [0, 16)
        int c4 = idx4 & 31;
        int row = row0 + r;
        if (row < n) {
            float inv = cnt ? 1.0f / fmaxf(cnt[row], 1.0f) : 1.0f;
            float4 mv = reinterpret_cast<const float4*>(agg + (size_t)row * FDIM)[c4];
            float4 xv = reinterpret_cast<const float4*>(xin + (size_t)row * FDIM)[c4];
            float* mp = &m_s[r][c4 * 4];
            mp[0] = mv.x * inv; mp[1] = mv.y * inv; mp[2] = mv.z * inv; mp[3] = mv.w * inv;
            float* xp = &x_s[r][c4 * 4];
            xp[0] = xv.x; xp[1] = xv.y; xp[2] = xv.z; xp[3] = xv.w;
        }
    }
    __syncthreads();

    int j = tid & 127;
    int rh = tid >> 7;
    float acc[8];
    float bj = bias[j];
#pragma unroll
    for (int r = 0; r < 8; ++r) acc[r] = bj;

#pragma unroll 4
    for (int k = 0; k < FDIM; ++k) {
        float wl = Wl[k * FDIM + j];
        float wr = Wr[k * FDIM + j];
#pragma unroll
        for (int r = 0; r < 8; ++r) {
            acc[r] += m_s[rh * 8 + r][k] * wl + x_s[rh * 8 + r][k] * wr;
        }
    }

#pragma unroll
    for (int r = 0; r < 8; ++r) {
        int row = row0 + rh * 8 + r;
        if (row < n) {
            float v = acc[r];
            if (RELU) v = fmaxf(v, 0.0f);
            out[(size_t)row * FDIM + j] = v;
        }
    }
}

extern "C" void kernel_launch(void* const* d_in, const int* in_sizes, int n_in,
                              void* d_out, int out_size, void* d_ws, size_t ws_size,
                              hipStream_t stream) {
    const float* x   = (const float*)d_in[0];
    const int*   ei  = (const int*)d_in[1];   // JAX x64 off -> int32
    const float* Wl0 = (const float*)d_in[2];
    const float* Wr0 = (const float*)d_in[3];
    const float* b0  = (const float*)d_in[4];
    const float* Wl1 = (const float*)d_in[5];
    const float* Wr1 = (const float*)d_in[6];
    const float* b1  = (const float*)d_in[7];

    int N = in_sizes[0] / FDIM;   // 50000
    int E = in_sizes[1] / 2;      // 800000
    const int* src = ei;
    const int* dst = ei + E;

    size_t featBytes = (size_t)N * FDIM * sizeof(float);
    int gemmBlocks = (N + 15) / 16;
    int edgeBlocks = (E + 255) / 256;
    int nb = (N + 255) / 256;                 // scan blocks (196 <= 256)

    // CSR workspace layout
    const size_t o_deg  = 0;                  // N ints
    const size_t o_rp   = 0x40000;            // (N+1) ints
    const size_t o_cur  = 0x80000;            // N ints
    const size_t o_bsum = 0xC0000;            // nb ints
    const size_t o_eid  = 0x100000;           // E ints
    const size_t o_h    = 0x440000;           // N*FDIM floats
    const size_t need   = o_h + featBytes;    // ~30.06 MB

    float* msg = (float*)d_out;               // aggregation output / final out

    if (ws_size >= need) {
        // ---------------- CSR gather path ----------------
        int* deg    = (int*)((char*)d_ws + o_deg);
        int* rp     = (int*)((char*)d_ws + o_rp);
        int* cursor = (int*)((char*)d_ws + o_cur);
        int* bsum   = (int*)((char*)d_ws + o_bsum);
        int* eid    = (int*)((char*)d_ws + o_eid);
        float* h    = (float*)((char*)d_ws + o_h);

        hipMemsetAsync(deg, 0, (size_t)N * sizeof(int), stream);
        hist_kernel<<<edgeBlocks, 256, 0, stream>>>(dst, deg, E);
        scan1_kernel<<<nb, 256, 0, stream>>>(deg, rp, bsum, N);
        scan2_kernel<<<1, 256, 0, stream>>>(bsum, nb);
        scan3_kernel<<<(N + 256) / 256, 256, 0, stream>>>(rp, bsum, cursor, N, E);
        fill_kernel<<<edgeBlocks, 256, 0, stream>>>(src, dst, cursor, eid, E);

        int gatherBlocks = (N + 3) / 4;       // 4 waves/block, 1 node/wave
        // layer 0
        gather_kernel<<<gatherBlocks, 256, 0, stream>>>(x, rp, eid, msg, N);
        gemm_kernel<true><<<gemmBlocks, 256, 0, stream>>>(msg, nullptr, x, Wl0, Wr0, b0, h, N);
        // layer 1
        gather_kernel<<<gatherBlocks, 256, 0, stream>>>(h, rp, eid, msg, N);
        gemm_kernel<false><<<gemmBlocks, 256, 0, stream>>>(msg, nullptr, h, Wl1, Wr1, b1, msg, N);
    } else {
        // ---------------- fallback: proven R2 atomic path ----------------
        float* cnt = (float*)d_ws;
        float* h   = (float*)((char*)d_ws + (1 << 18));

        hipMemsetAsync(cnt, 0, (size_t)N * sizeof(float), stream);
        degree_kernel<<<edgeBlocks, 256, 0, stream>>>(dst, cnt, E);

        hipMemsetAsync(msg, 0, featBytes, stream);
        scatter_kernel<<<(E * 64 + 255) / 256, 256, 0, stream>>>(x, src, dst, msg, E);
        gemm_kernel<true><<<gemmBlocks, 256, 0, stream>>>(msg, cnt, x, Wl0, Wr0, b0, h, N);

        hipMemsetAsync(msg, 0, featBytes, stream);
        scatter_kernel<<<(E * 64 + 255) / 256, 256, 0, stream>>>(h, src, dst, msg, E);
        gemm_kernel<false><<<gemmBlocks, 256, 0, stream>>>(msg, cnt, h, Wl1, Wr1, b1, msg, N);
    }
}

// Round 4
// 217.981 us; speedup vs baseline: 7.3133x; 1.9019x over previous
//
#include <hip/hip_runtime.h>

#define FDIM 128

typedef __attribute__((ext_vector_type(4))) float f32x4;
typedef __attribute__((ext_vector_type(8))) short s16x8;
typedef __attribute__((ext_vector_type(4))) short s16x4;

__device__ inline unsigned short f2bf(float f) {      // RNE f32->bf16
    unsigned u = __builtin_bit_cast(unsigned, f);
    u += 0x7FFFu + ((u >> 16) & 1u);
    return (unsigned short)(u >> 16);
}

// ======================= CSR build =======================
__global__ void hist_kernel(const int* __restrict__ dst, int* __restrict__ deg, int E) {
    int e = blockIdx.x * blockDim.x + threadIdx.x;
    if (e < E) atomicAdd(&deg[dst[e]], 1);
}

__global__ void scan1_kernel(const int* __restrict__ deg, int* __restrict__ rp,
                             int* __restrict__ bsum, int N) {
    __shared__ int s[256];
    int i = blockIdx.x * 256 + threadIdx.x;
    int v = (i < N) ? deg[i] : 0;
    s[threadIdx.x] = v;
    __syncthreads();
    for (int off = 1; off < 256; off <<= 1) {
        int t = (threadIdx.x >= off) ? s[threadIdx.x - off] : 0;
        __syncthreads();
        s[threadIdx.x] += t;
        __syncthreads();
    }
    if (i < N) rp[i] = s[threadIdx.x] - v;
    if (threadIdx.x == 255) bsum[blockIdx.x] = s[255];
}

__global__ void scan2_kernel(int* __restrict__ bsum, int nb) {
    __shared__ int s[256];
    int v = (threadIdx.x < (unsigned)nb) ? bsum[threadIdx.x] : 0;
    s[threadIdx.x] = v;
    __syncthreads();
    for (int off = 1; off < 256; off <<= 1) {
        int t = (threadIdx.x >= off) ? s[threadIdx.x - off] : 0;
        __syncthreads();
        s[threadIdx.x] += t;
        __syncthreads();
    }
    if (threadIdx.x < (unsigned)nb) bsum[threadIdx.x] = s[threadIdx.x] - v;
}

__global__ void scan3_kernel(int* __restrict__ rp, const int* __restrict__ bsum,
                             int* __restrict__ cursor, int N, int E) {
    int i = blockIdx.x * 256 + threadIdx.x;
    if (i < N) {
        int v = rp[i] + bsum[blockIdx.x];
        rp[i] = v;
        cursor[i] = v;
    } else if (i == N) {
        rp[N] = E;
    }
}

__global__ void fill_kernel(const int* __restrict__ src, const int* __restrict__ dst,
                            int* __restrict__ cursor, int* __restrict__ eid, int E) {
    int e = blockIdx.x * blockDim.x + threadIdx.x;
    if (e < E) {
        int p = atomicAdd(&cursor[dst[e]], 1);
        eid[p] = src[e];
    }
}

// ======================= bf16 prep =======================
__global__ void prep_x_kernel(const float* __restrict__ x, short* __restrict__ xb, int n4) {
    int i = blockIdx.x * blockDim.x + threadIdx.x;
    if (i < n4) {
        float4 v = reinterpret_cast<const float4*>(x)[i];
        s16x4 o;
        o[0] = (short)f2bf(v.x); o[1] = (short)f2bf(v.y);
        o[2] = (short)f2bf(v.z); o[3] = (short)f2bf(v.w);
        reinterpret_cast<s16x4*>(xb)[i] = o;
    }
}

// Wt[layer][n][k]: k<128 -> Wl[k][n], k>=128 -> Wr[k-128][n]  (bf16, n-major rows of 256)
__global__ void prep_w_kernel(const float* __restrict__ Wl0, const float* __restrict__ Wr0,
                              const float* __restrict__ Wl1, const float* __restrict__ Wr1,
                              short* __restrict__ Wt0, short* __restrict__ Wt1) {
    int g = blockIdx.x * blockDim.x + threadIdx.x;   // [0, 65536)
    int n = g & 127;
    int k = (g >> 7) & 255;
    int layer = g >> 15;
    const float* Wl = layer ? Wl1 : Wl0;
    const float* Wr = layer ? Wr1 : Wr0;
    short* Wt = layer ? Wt1 : Wt0;
    float v = (k < 128) ? Wl[k * 128 + n] : Wr[(k - 128) * 128 + n];
    Wt[n * 256 + k] = (short)f2bf(v);
}

// ============ mean-aggregate via gather (bf16 in/out, fp32 accum) ============
// One wave per node; lane l covers cols {2l, 2l+1} (4B/lane -> 256B coalesced row reads).
__global__ void gather_kernel(const short* __restrict__ xb, const int* __restrict__ rp,
                              const int* __restrict__ eid, short* __restrict__ mb, int N) {
    int node = blockIdx.x * (blockDim.x >> 6) + (threadIdx.x >> 6);
    int lane = threadIdx.x & 63;
    if (node >= N) return;
    int beg = rp[node], end = rp[node + 1];
    float ax = 0.f, ay = 0.f;
    int k = beg;
    for (; k + 4 <= end; k += 4) {
        int s0 = eid[k], s1 = eid[k + 1], s2 = eid[k + 2], s3 = eid[k + 3];
        unsigned u0 = reinterpret_cast<const unsigned*>(xb + (size_t)s0 * FDIM)[lane];
        unsigned u1 = reinterpret_cast<const unsigned*>(xb + (size_t)s1 * FDIM)[lane];
        unsigned u2 = reinterpret_cast<const unsigned*>(xb + (size_t)s2 * FDIM)[lane];
        unsigned u3 = reinterpret_cast<const unsigned*>(xb + (size_t)s3 * FDIM)[lane];
        ax += __builtin_bit_cast(float, u0 << 16) + __builtin_bit_cast(float, u1 << 16)
            + __builtin_bit_cast(float, u2 << 16) + __builtin_bit_cast(float, u3 << 16);
        ay += __builtin_bit_cast(float, u0 & 0xFFFF0000u) + __builtin_bit_cast(float, u1 & 0xFFFF0000u)
            + __builtin_bit_cast(float, u2 & 0xFFFF0000u) + __builtin_bit_cast(float, u3 & 0xFFFF0000u);
    }
    for (; k < end; ++k) {
        int s = eid[k];
        unsigned u = reinterpret_cast<const unsigned*>(xb + (size_t)s * FDIM)[lane];
        ax += __builtin_bit_cast(float, u << 16);
        ay += __builtin_bit_cast(float, u & 0xFFFF0000u);
    }
    float inv = (end > beg) ? 1.0f / (float)(end - beg) : 0.0f;
    unsigned lo = f2bf(ax * inv), hi = f2bf(ay * inv);
    reinterpret_cast<unsigned*>(mb + (size_t)node * FDIM)[lane] = lo | (hi << 16);
}

// ===================== MFMA GEMM: out = [mean|x] @ [Wl;Wr] + b =====================
// Block: 64 rows x 128 cols, 4 waves (each 64x32). K=256 staged once in LDS (swizzled).
// In-place safe for outb==Ax: block stages only its own 64 rows before writing them.
template <bool RELU, bool OUTF32>
__global__ __launch_bounds__(256, 2)
void gemm_mfma_kernel(const short* __restrict__ Am, const short* Ax,
                      const short* __restrict__ Wt, const float* __restrict__ bias,
                      float* outf, short* outb, int n) {
    __shared__ short A_lds[64 * 256];   // 32 KB
    const int tid = threadIdx.x;
    const int w = tid >> 6, l = tid & 63;
    const int row0 = blockIdx.x * 64;

    // All 16 B-fragments up front (weights are L2-resident, shared by all blocks).
    s16x8 bfr[8][2];
    {
        const short* wb = Wt + ((32 * w + (l & 15)) * 256 + 8 * (l >> 4));
#pragma unroll
        for (int kc = 0; kc < 8; ++kc)
#pragma unroll
            for (int cf = 0; cf < 2; ++cf)
                bfr[kc][cf] = *reinterpret_cast<const s16x8*>(wb + cf * 16 * 256 + kc * 32);
    }

    // Stage A tile [64][256]: k<128 from Am(mean), k>=128 from Ax(x/h). XOR-swizzled 16B chunks.
#pragma unroll
    for (int i = 0; i < 8; ++i) {
        int c = tid + 256 * i;          // [0, 2048)
        int r = c >> 5;                 // row in tile
        int ck = c & 31;                // 16B chunk within row (k0 = ck*8)
        int row = row0 + r;
        s16x8 v;
        if (row < n) {
            const short* sp = (ck < 16) ? (Am + (size_t)row * FDIM + ck * 8)
                                        : (Ax + (size_t)row * FDIM + (ck - 16) * 8);
            v = *reinterpret_cast<const s16x8*>(sp);
        } else {
#pragma unroll
            for (int j = 0; j < 8; ++j) v[j] = 0;
        }
        int byte = r * 512 + ((ck * 16) ^ ((r & 7) << 4));
        *reinterpret_cast<s16x8*>(reinterpret_cast<char*>(A_lds) + byte) = v;
    }
    __syncthreads();

    f32x4 acc[4][2];
    {
        float b0 = bias[32 * w + (l & 15)];
        float b1 = bias[32 * w + 16 + (l & 15)];
#pragma unroll
        for (int rf = 0; rf < 4; ++rf)
#pragma unroll
            for (int i = 0; i < 4; ++i) { acc[rf][0][i] = b0; acc[rf][1][i] = b1; }
    }

    const int arow = l & 15;
    const int aq16 = 16 * (l >> 4);
#pragma unroll
    for (int kc = 0; kc < 8; ++kc) {
        s16x8 afr[4];
#pragma unroll
        for (int rf = 0; rf < 4; ++rf) {
            int r = 16 * rf + arow;
            int kbyte = 64 * kc + aq16;
            int byte = r * 512 + (kbyte ^ ((r & 7) << 4));
            afr[rf] = *reinterpret_cast<const s16x8*>(reinterpret_cast<const char*>(A_lds) + byte);
        }
#pragma unroll
        for (int rf = 0; rf < 4; ++rf)
#pragma unroll
            for (int cf = 0; cf < 2; ++cf)
                acc[rf][cf] = __builtin_amdgcn_mfma_f32_16x16x32_bf16(afr[rf], bfr[kc][cf], acc[rf][cf], 0, 0, 0);
    }

    // Epilogue: D col = lane&15, row = 4*(lane>>4)+reg.
    const int ocol = 32 * w + (l & 15);
    const int orow = 4 * (l >> 4);
#pragma unroll
    for (int rf = 0; rf < 4; ++rf)
#pragma unroll
        for (int cf = 0; cf < 2; ++cf)
#pragma unroll
            for (int i = 0; i < 4; ++i) {
                int row = row0 + 16 * rf + orow + i;
                if (row < n) {
                    float v = acc[rf][cf][i];
                    if (RELU) v = fmaxf(v, 0.0f);
                    if (OUTF32) outf[(size_t)row * FDIM + ocol + 16 * cf] = v;
                    else        outb[(size_t)row * FDIM + ocol + 16 * cf] = (short)f2bf(v);
                }
            }
}

// ===================== fallback: atomic scatter path (R2, proven) =====================
__global__ void degree_kernel(const int* __restrict__ dst, float* __restrict__ cnt, int E) {
    int e = blockIdx.x * blockDim.x + threadIdx.x;
    if (e < E) atomicAdd(&cnt[dst[e]], 1.0f);
}

__global__ void scatter_kernel(const float* __restrict__ x, const int* __restrict__ src,
                               const int* __restrict__ dst, float* __restrict__ msg, int E) {
    int gt = blockIdx.x * blockDim.x + threadIdx.x;
    int e = gt >> 6;
    int lane = gt & 63;
    if (e >= E) return;
    int s = src[e];
    int d = dst[e];
    float2 v = reinterpret_cast<const float2*>(x + (size_t)s * FDIM)[lane];
    float* md = msg + (size_t)d * FDIM + 2 * lane;
    atomicAdd(md, v.x);
    atomicAdd(md + 1, v.y);
}

template <bool RELU>
__global__ void gemm_kernel(const float* agg, const float* cnt,
                            const float* __restrict__ xin, const float* __restrict__ Wl,
                            const float* __restrict__ Wr, const float* __restrict__ bias,
                            float* out, int n) {
    const int ROWS = 16;
    __shared__ float m_s[ROWS][FDIM];
    __shared__ float x_s[ROWS][FDIM];
    int tid = threadIdx.x;
    int row0 = blockIdx.x * ROWS;
#pragma unroll
    for (int i = 0; i < 2; ++i) {
        int idx4 = tid + i * 256;
        int r = idx4 >> 5;
        int c4 = idx4 & 31;
        int row = row0 + r;
        if (row < n) {
            float inv = cnt ? 1.0f / fmaxf(cnt[row], 1.0f) : 1.0f;
            float4 mv = reinterpret_cast<const float4*>(agg + (size_t)row * FDIM)[c4];
            float4 xv = reinterpret_cast<const float4*>(xin + (size_t)row * FDIM)[c4];
            float* mp = &m_s[r][c4 * 4];
            mp[0] = mv.x * inv; mp[1] = mv.y * inv; mp[2] = mv.z * inv; mp[3] = mv.w * inv;
            float* xp = &x_s[r][c4 * 4];
            xp[0] = xv.x; xp[1] = xv.y; xp[2] = xv.z; xp[3] = xv.w;
        }
    }
    __syncthreads();
    int j = tid & 127;
    int rh = tid >> 7;
    float acc[8];
    float bj = bias[j];
#pragma unroll
    for (int r = 0; r < 8; ++r) acc[r] = bj;
#pragma unroll 4
    for (int k = 0; k < FDIM; ++k) {
        float wl = Wl[k * FDIM + j];
        float wr = Wr[k * FDIM + j];
#pragma unroll
        for (int r = 0; r < 8; ++r)
            acc[r] += m_s[rh * 8 + r][k] * wl + x_s[rh * 8 + r][k] * wr;
    }
#pragma unroll
    for (int r = 0; r < 8; ++r) {
        int row = row0 + rh * 8 + r;
        if (row < n) {
            float v = acc[r];
            if (RELU) v = fmaxf(v, 0.0f);
            out[(size_t)row * FDIM + j] = v;
        }
    }
}

extern "C" void kernel_launch(void* const* d_in, const int* in_sizes, int n_in,
                              void* d_out, int out_size, void* d_ws, size_t ws_size,
                              hipStream_t stream) {
    const float* x   = (const float*)d_in[0];
    const int*   ei  = (const int*)d_in[1];
    const float* Wl0 = (const float*)d_in[2];
    const float* Wr0 = (const float*)d_in[3];
    const float* b0  = (const float*)d_in[4];
    const float* Wl1 = (const float*)d_in[5];
    const float* Wr1 = (const float*)d_in[6];
    const float* b1  = (const float*)d_in[7];

    int N = in_sizes[0] / FDIM;   // 50000
    int E = in_sizes[1] / 2;      // 800000
    const int* src = ei;
    const int* dst = ei + E;

    size_t featBytes  = (size_t)N * FDIM * sizeof(float);   // 25.6 MB
    size_t featBytesB = (size_t)N * FDIM * sizeof(short);   // 12.8 MB
    int edgeBlocks = (E + 255) / 256;
    int nb = (N + 255) / 256;

    // workspace layout (total == 30,056,448 B, same as R3's proven-fitting need)
    const size_t o_deg  = 0;                    // N ints
    const size_t o_rp   = 0x40000;              // N+1 ints
    const size_t o_cur  = 0x80000;              // N ints
    const size_t o_bsum = 0xC0000;              // nb ints
    const size_t o_wt0  = 0xD0000;              // 128*256 bf16 = 64 KB
    const size_t o_wt1  = 0xE0000;              // 64 KB
    const size_t o_eid  = 0x100000;             // E ints
    const size_t o_xb   = 0x440000;             // N*128 bf16 (x, then h in-place)
    const size_t o_mb   = o_xb + featBytesB;    // N*128 bf16 (mean, reused per layer)
    const size_t need   = o_mb + featBytesB;

    if (ws_size >= need) {
        int*   deg    = (int*)((char*)d_ws + o_deg);
        int*   rp     = (int*)((char*)d_ws + o_rp);
        int*   cursor = (int*)((char*)d_ws + o_cur);
        int*   bsum   = (int*)((char*)d_ws + o_bsum);
        short* Wt0    = (short*)((char*)d_ws + o_wt0);
        short* Wt1    = (short*)((char*)d_ws + o_wt1);
        int*   eid    = (int*)((char*)d_ws + o_eid);
        short* xb     = (short*)((char*)d_ws + o_xb);   // x bf16, overwritten by h bf16
        short* mb     = (short*)((char*)d_ws + o_mb);
        float* outF   = (float*)d_out;

        // CSR build
        hipMemsetAsync(deg, 0, (size_t)N * sizeof(int), stream);
        hist_kernel<<<edgeBlocks, 256, 0, stream>>>(dst, deg, E);
        scan1_kernel<<<nb, 256, 0, stream>>>(deg, rp, bsum, N);
        scan2_kernel<<<1, 256, 0, stream>>>(bsum, nb);
        scan3_kernel<<<(N + 256) / 256, 256, 0, stream>>>(rp, bsum, cursor, N, E);
        fill_kernel<<<edgeBlocks, 256, 0, stream>>>(src, dst, cursor, eid, E);

        // bf16 prep
        prep_w_kernel<<<256, 256, 0, stream>>>(Wl0, Wr0, Wl1, Wr1, Wt0, Wt1);
        prep_x_kernel<<<(N * FDIM / 4 + 255) / 256, 256, 0, stream>>>(x, xb, N * FDIM / 4);

        int gatherBlocks = (N + 3) / 4;
        int gemmBlocks   = (N + 63) / 64;
        // layer 0: h(bf16, in-place over xb) = relu([mean|x] @ Wcat0 + b0)
        gather_kernel<<<gatherBlocks, 256, 0, stream>>>(xb, rp, eid, mb, N);
        gemm_mfma_kernel<true, false><<<gemmBlocks, 256, 0, stream>>>(mb, xb, Wt0, b0, nullptr, xb, N);
        // layer 1: out(f32) = [mean(h)|h] @ Wcat1 + b1
        gather_kernel<<<gatherBlocks, 256, 0, stream>>>(xb, rp, eid, mb, N);
        gemm_mfma_kernel<false, true><<<gemmBlocks, 256, 0, stream>>>(mb, xb, Wt1, b1, outF, nullptr, N);
    } else {
        // fallback: proven atomic path
        float* cnt = (float*)d_ws;
        float* h   = (float*)((char*)d_ws + (1 << 18));
        float* msg = (float*)d_out;
        int gemmBlocks = (N + 15) / 16;

        hipMemsetAsync(cnt, 0, (size_t)N * sizeof(float), stream);
        degree_kernel<<<edgeBlocks, 256, 0, stream>>>(dst, cnt, E);

        hipMemsetAsync(msg, 0, featBytes, stream);
        scatter_kernel<<<(E * 64 + 255) / 256, 256, 0, stream>>>(x, src, dst, msg, E);
        gemm_kernel<true><<<gemmBlocks, 256, 0, stream>>>(msg, cnt, x, Wl0, Wr0, b0, h, N);

        hipMemsetAsync(msg, 0, featBytes, stream);
        scatter_kernel<<<(E * 64 + 255) / 256, 256, 0, stream>>>(h, src, dst, msg, E);
        gemm_kernel<false><<<gemmBlocks, 256, 0, stream>>>(msg, cnt, h, Wl1, Wr1, b1, msg, N);
    }
}